// Round 3
// baseline (282.722 us; speedup 1.0000x reference)
//
#include <hip/hip_runtime.h>
#include <stdint.h>

#define TT 512
#define BTW 16   // batches per wg: 8 per stream; grid 256 -> 1 wg/CU
#define XSTR 516 // x row stride (floats)

typedef float    f32x4 __attribute__((ext_vector_type(4)));
typedef float    f32x2 __attribute__((ext_vector_type(2)));
typedef short    s16x8 __attribute__((ext_vector_type(8)));
typedef __fp16   h16x2 __attribute__((ext_vector_type(2)));
typedef _Float16 f16x8 __attribute__((ext_vector_type(8)));

#define MFMA_F16(A, B, C) \
    __builtin_amdgcn_mfma_f32_16x16x32_f16( \
        __builtin_bit_cast(f16x8, (A)), (B), (C), 0, 0, 0)

#define LOG2E  1.442695040888963f
#define LOG2E2 2.885390081777927f

// R11: forced anti-phase wave specialization. One 512-thread wg per CU,
// two independent 8-batch streams: P = waves 0-3, Q = waves 4-7 (round-
// robin wave->SIMD pairs one P with one Q per SIMD). 2 barriers/step with
// rotated bodies: phase A = P:{VALU,write} || Q:{read,MFMA}; phase B =
// swap. Partner's LDS-read+MFMA latency overlaps my VALU chain by
// construction (R10's lesson: free-running wgs phase-lock, TLP never
// filled the ~350cyc/step chain hole). Per-stream structure = R9 verbatim
// (zero-conflict exchange, f32x2 packed VALU, fp16 MFMA); single-buffered
// h per stream (2 barriers/step make it safe). All gates split-MFMA
// (parallel pair + add), issue order R,N,Z = consumption order.
__global__ __launch_bounds__(512, 2) void gru_scan_kernel(
    const float* __restrict__ x,     // (4096, 512, 1)
    const float* __restrict__ Wih,   // (192, 1)
    const float* __restrict__ Whh,   // (192, 64)
    const float* __restrict__ bih,   // (192)
    const float* __restrict__ bhh,   // (192)
    const float* __restrict__ Wout,  // (1, 64)
    const float* __restrict__ bout,  // (1)
    float* __restrict__ out)         // (4096, 1)
{
    __shared__ __align__(16) float xs[BTW * XSTR];   // 33 KB
    __shared__ __align__(16) short hbufs[2][1024];   // [stream][slot*8+j], 4 KB
    __shared__ float outp[8][8];

    const int tid  = threadIdx.x;
    const int w    = tid >> 6;
    const int L    = tid & 63;
    const int n16  = L & 15;
    const int quad = L >> 4;
    const int isP  = (w < 4);
    const int sw   = isP ? 0 : 1;    // stream index
    const int q    = (w & 3) * 16 + n16;   // hidden col owned by this lane
    const int b0   = blockIdx.x * BTW;
    const int bs   = sw * 8;         // stream's first batch within wg

    // ---- stage x batch-major: xs[b][t] (2048 f32x4, 4 per thread) ----
    #pragma unroll
    for (int k = 0; k < 4; ++k) {
        int idx = tid + k * 512;          // 0..2047
        int row = idx >> 7;               // batch row 0..15
        int t4  = idx & 127;              // t/4
        f32x4 v = *(const f32x4*)(x + (size_t)(b0 + row) * TT + t4 * 4);
        *(f32x4*)(xs + row * XSTR + t4 * 4) = v;
    }
    // ---- zero both stream h buffers (4096 B = 1024 u32) ----
    ((unsigned*)hbufs)[tid]       = 0u;
    ((unsigned*)hbufs)[tid + 512] = 0u;

    // ---- per-lane constants (gate scales folded) ----
    const float wr2   = -LOG2E  * Wih[q];
    const float wz2   = -LOG2E  * Wih[64 + q];
    const float wn2   =  LOG2E2 * Wih[128 + q];
    const float bR2   = -LOG2E  * (bih[q]      + bhh[q]);
    const float bZ2   = -LOG2E  * (bih[64 + q] + bhh[64 + q]);
    const float bN2   =  LOG2E2 * bhh[128 + q];
    const float bihn2 =  LOG2E2 * bih[128 + q];
    const float wo    = Wout[q];

    const f32x4 bR4   = {bR2, bR2, bR2, bR2};
    const f32x4 bZ4   = {bZ2, bZ2, bZ2, bZ2};
    const f32x4 bN4   = {bN2, bN2, bN2, bN2};
    const f32x4 zero4 = {0.f, 0.f, 0.f, 0.f};

    // ---- W_hh B-fragments (scaled), fp16 RNE ----
    f16x8 Bf[3][2];
    #pragma unroll
    for (int g = 0; g < 3; ++g) {
        const float sg = (g == 2) ? LOG2E2 : -LOG2E;
        #pragma unroll
        for (int c = 0; c < 2; ++c) {
            const float* p = Whh + ((g * 64 + q) * 64 + c * 32 + quad * 8);
            #pragma unroll
            for (int j = 0; j < 8; ++j)
                Bf[g][c][j] = (_Float16)(p[j] * sg);
        }
    }

    // persistent h (fp32): lane handles stream batches quad*2 + {0,1}
    float hD0 = 0.f, hD1 = 0.f;
    f32x2 hm1 = {-1.f, -1.f};    // h - 1, carried off-chain

    // ---- R9's proven zero-conflict exchange addressing ----
    const int kg   = q >> 3;
    const int sxor = (kg & 1) * 4;
    int waddr[2];
    #pragma unroll
    for (int p = 0; p < 2; ++p)
        waddr[p] = (kg * 16 + ((p * 4 + quad) ^ sxor)) * 8 + (q & 7);

    const int permx = ((n16 & 3) * 4 + (n16 >> 2)) ^ ((quad & 1) * 4);
    const int rslot = quad * 16 + permx;

    short* myh = hbufs[sw];
    const s16x8* hbv = (const s16x8*)myh;   // 128 slots of 8 shorts
    const float* xrow0 = xs + (bs + quad * 2) * XSTR;
    const float* xrow1 = xrow0 + XSTR;

    // persistent MFMA accumulators (survive the barrier between phases)
    f32x4 accRa, accRb, accNa, accNb, accZa, accZb;

    auto rm = [&]() {   // read h + all 6 MFMAs (split C-chains; order R,N,Z)
        s16x8 A0 = hbv[rslot];
        s16x8 A1 = hbv[64 + rslot];
        accRa = MFMA_F16(A0, Bf[0][0], bR4);
        accRb = MFMA_F16(A1, Bf[0][1], zero4);
        accNa = MFMA_F16(A0, Bf[2][0], bN4);
        accNb = MFMA_F16(A1, Bf[2][1], zero4);
        accZa = MFMA_F16(A0, Bf[1][0], bZ4);
        accZb = MFMA_F16(A1, Bf[1][1], zero4);
    };

    auto vw = [&](f32x2 xv) {   // gate math + h update + write h to LDS
        f32x2 aR = {accRa[0] + accRb[0], accRa[1] + accRb[1]};
        f32x2 aN = {accNa[0] + accNb[0], accNa[1] + accNb[1]};
        f32x2 aZ = {accZa[0] + accZb[0], accZa[1] + accZb[1]};

        f32x2 ar = xv * wr2 + aR;
        f32x2 Er = {__builtin_amdgcn_exp2f(ar[0]), __builtin_amdgcn_exp2f(ar[1])};
        f32x2 DR = Er + 1.0f;
        f32x2 r  = {__builtin_amdgcn_rcpf(DR[0]), __builtin_amdgcn_rcpf(DR[1])};
        f32x2 xn = xv * wn2 + bihn2;
        f32x2 an = r * aN + xn;
        f32x2 En = {__builtin_amdgcn_exp2f(an[0]), __builtin_amdgcn_exp2f(an[1])};
        f32x2 DN = En + 1.0f;
        f32x2 az = xv * wz2 + aZ;
        f32x2 Ez = {__builtin_amdgcn_exp2f(az[0]), __builtin_amdgcn_exp2f(az[1])};
        f32x2 DZ = Ez + 1.0f;
        f32x2 P  = DZ * DN;
        f32x2 iq = {__builtin_amdgcn_rcpf(P[0]), __builtin_amdgcn_rcpf(P[1])};
        f32x2 z  = iq * DN;                  // = 1/DZ = sigmoid(pre_z)
        f32x2 rn = iq * DZ;                  // = 1/DN
        f32x2 n  = rn * -2.0f + 1.0f;        // tanh
        f32x2 s  = rn *  2.0f + hm1;         // h_prev - n
        f32x2 hn = z * s + n;                // (1-z)n + z h

        hD0 = hn[0]; hD1 = hn[1];
        hm1 = hn - 1.0f;

        h16x2 hpk = __builtin_amdgcn_cvt_pkrtz(hn[0], hn[1]);
        unsigned upk = __builtin_bit_cast(unsigned, hpk);
        myh[waddr[0]] = (short)(upk & 0xffffu);
        myh[waddr[1]] = (short)(upk >> 16);
    };

    __syncthreads();          // x + hbuf init visible

    if (isP) rm();            // P prologue: gates for h_P(0) from h=0

    f32x4 xa = *(const f32x4*)(xrow0);
    f32x4 xb = *(const f32x4*)(xrow1);
    for (int t = 0; t < TT; t += 4) {
        const int tn = (t + 4 < TT) ? t + 4 : 0;   // prefetch next x group
        f32x4 xan = *(const f32x4*)(xrow0 + tn);
        f32x4 xbn = *(const f32x4*)(xrow1 + tn);
        #pragma unroll
        for (int j = 0; j < 4; ++j) {
            f32x2 xv = {xa[j], xb[j]};
            __syncthreads();                 // phase A boundary
            if (isP) vw(xv); else rm();
            __syncthreads();                 // phase B boundary
            if (isP) rm(); else vw(xv);
        }
        xa = xan; xb = xbn;
    }
    // after loop: P produced h_P(TT-1) in its last vw (phase A of last
    // step); Q produced h_Q(TT-1) in phase B. P's trailing rm is benign.

    // ---- epilogue: out[b] = sum_q h[b][q]*Wout[q] + bout ----
    float p0 = hD0 * wo;
    float p1 = hD1 * wo;
    #pragma unroll
    for (int mask = 1; mask <= 8; mask <<= 1) {
        p0 += __shfl_xor(p0, mask, 64);
        p1 += __shfl_xor(p1, mask, 64);
    }
    if (n16 == 0) {
        outp[w][quad * 2]     = p0;
        outp[w][quad * 2 + 1] = p1;
    }
    __syncthreads();
    if (tid < BTW) {
        int ss = tid >> 3;        // stream
        int c  = tid & 7;         // batch within stream
        out[b0 + tid] = outp[ss * 4 + 0][c] + outp[ss * 4 + 1][c] +
                        outp[ss * 4 + 2][c] + outp[ss * 4 + 3][c] + bout[0];
    }
}

extern "C" void kernel_launch(void* const* d_in, const int* in_sizes, int n_in,
                              void* d_out, int out_size, void* d_ws, size_t ws_size,
                              hipStream_t stream) {
    (void)in_sizes; (void)n_in; (void)d_ws; (void)ws_size; (void)out_size;
    const float* x    = (const float*)d_in[0];
    const float* Wih  = (const float*)d_in[1];
    const float* Whh  = (const float*)d_in[2];
    const float* bih  = (const float*)d_in[3];
    const float* bhh  = (const float*)d_in[4];
    const float* Wout = (const float*)d_in[5];
    const float* bout = (const float*)d_in[6];
    float* out = (float*)d_out;

    gru_scan_kernel<<<dim3(4096 / BTW), dim3(512), 0, stream>>>(
        x, Wih, Whh, bih, bhh, Wout, bout, out);
}

// Round 4
// 255.715 us; speedup vs baseline: 1.1056x; 1.1056x over previous
//
#include <hip/hip_runtime.h>
#include <stdint.h>

#define TT 512
#define BTW 16   // batches per wg; grid 4096/16 = 256 -> exactly 1 wg/CU
#define XSTR 516 // x row stride (floats)

typedef float    f32x4 __attribute__((ext_vector_type(4)));
typedef short    s16x8 __attribute__((ext_vector_type(8)));
typedef __fp16   h16x2 __attribute__((ext_vector_type(2)));
typedef _Float16 f16x8 __attribute__((ext_vector_type(8)));

#define MFMA_F16(A, B, C) \
    __builtin_amdgcn_mfma_f32_16x16x32_f16( \
        __builtin_bit_cast(f16x8, (A)), (B), (C), 0, 0, 0)

#define LOG2E  1.442695040888963f
#define LOG2E2 2.885390081777927f

// R12: zero-contention / max-economy. BT=16 fills all 16 MFMA A-rows
// (6 MFMA/step/wave for 16 batches = 1.5/batch, the 16x16x32 optimum);
// grid 256 = 1 wg/CU so each wave is ALONE on its SIMD: no co-resident
// wg contention or barrier skew (R9 paid ~320cyc/step for it; R10/R11
// proved TLP never fills the chain). 4 values/lane = two independent
// packed gate chains that hide each other's trans latency.
// Exchange layout: h[row][k] fp16, 16B k-groups XOR-swizzled
// (group = kb ^ (row&7)): reads 2x ds_read_b128 bijective/even-spread,
// writes 4x ds_write_b16 <=2-way (free). Dbuf + 1 barrier/step.
__global__ __launch_bounds__(256, 1) void gru_scan_kernel(
    const float* __restrict__ x,     // (4096, 512, 1)
    const float* __restrict__ Wih,   // (192, 1)
    const float* __restrict__ Whh,   // (192, 64)
    const float* __restrict__ bih,   // (192)
    const float* __restrict__ bhh,   // (192)
    const float* __restrict__ Wout,  // (1, 64)
    const float* __restrict__ bout,  // (1)
    float* __restrict__ out)         // (4096, 1)
{
    __shared__ __align__(16) float xs[BTW * XSTR];   // 33 KB
    __shared__ __align__(16) short hbuf[2][1024];    // 4 KB; short-idx = row*64 + (kb^(row&7))*8 + (k&7)
    __shared__ float outp[4][BTW];

    const int tid  = threadIdx.x;
    const int w    = tid >> 6;
    const int L    = tid & 63;
    const int n16  = L & 15;
    const int quad = L >> 4;
    const int q    = w * 16 + n16;   // hidden col owned by this lane
    const int b0   = blockIdx.x * BTW;

    // ---- stage x batch-major: xs[b][t] (2048 f32x4, 8 per thread) ----
    #pragma unroll
    for (int k = 0; k < 8; ++k) {
        int idx = tid + k * 256;          // 0..2047
        int row = idx >> 7;               // batch row 0..15
        int t4  = idx & 127;              // t/4
        f32x4 v = *(const f32x4*)(x + (size_t)(b0 + row) * TT + t4 * 4);
        *(f32x4*)(xs + row * XSTR + t4 * 4) = v;
    }
    // ---- zero both h buffers (1024 u32) ----
    {
        unsigned* hz = (unsigned*)hbuf;
        hz[tid] = 0u; hz[tid + 256] = 0u; hz[tid + 512] = 0u; hz[tid + 768] = 0u;
    }

    // ---- per-lane constants (gate scales folded) ----
    const float wr2   = -LOG2E  * Wih[q];
    const float wz2   = -LOG2E  * Wih[64 + q];
    const float wn2   =  LOG2E2 * Wih[128 + q];
    const float bR2   = -LOG2E  * (bih[q]      + bhh[q]);
    const float bZ2   = -LOG2E  * (bih[64 + q] + bhh[64 + q]);
    const float bN2   =  LOG2E2 * bhh[128 + q];
    const float bihn2 =  LOG2E2 * bih[128 + q];
    const float wo    = Wout[q];

    const f32x4 bR4   = {bR2, bR2, bR2, bR2};
    const f32x4 bZ4   = {bZ2, bZ2, bZ2, bZ2};
    const f32x4 bN4   = {bN2, bN2, bN2, bN2};
    const f32x4 zero4 = {0.f, 0.f, 0.f, 0.f};

    // ---- W_hh B-fragments (scaled), fp16 RNE ----
    f16x8 Bf[3][2];
    #pragma unroll
    for (int g = 0; g < 3; ++g) {
        const float sg = (g == 2) ? LOG2E2 : -LOG2E;
        #pragma unroll
        for (int c = 0; c < 2; ++c) {
            const float* p = Whh + ((g * 64 + q) * 64 + c * 32 + quad * 8);
            #pragma unroll
            for (int j = 0; j < 8; ++j)
                Bf[g][c][j] = (_Float16)(p[j] * sg);
        }
    }

    // ---- exchange addressing ----
    // A-read: lane needs h[row=n16][k = quad*8+j (A0) / 32+quad*8+j (A1)]
    const int slot0 = n16 * 8 + ( quad      ^ (n16 & 7));
    const int slot1 = n16 * 8 + ((quad + 4) ^ (n16 & 7));
    // write: batch rows bq = quad*4+r, col q; kbw = q>>3
    int wa[4];
    #pragma unroll
    for (int r = 0; r < 4; ++r) {
        int bq = quad * 4 + r;
        wa[r] = bq * 64 + (((q >> 3) ^ (bq & 7)) * 8) + (q & 7);
    }

    const s16x8* hbv = (const s16x8*)hbuf;   // 128 slots per buffer
    const float* xr0 = xs + (quad * 4 + 0) * XSTR;
    const float* xr1 = xs + (quad * 4 + 1) * XSTR;
    const float* xr2 = xs + (quad * 4 + 2) * XSTR;
    const float* xr3 = xs + (quad * 4 + 3) * XSTR;

    // persistent h state (fp32), batches quad*4 + {0,1,2,3}
    f32x4 hlast = {0.f, 0.f, 0.f, 0.f};
    f32x4 hm1   = {-1.f, -1.f, -1.f, -1.f};   // h - 1, carried off-chain

    auto step = [&](int cur, f32x4 xv) {
        __syncthreads();

        s16x8 A0 = hbv[cur * 128 + slot0];
        s16x8 A1 = hbv[cur * 128 + slot1];

        // issue order = consumption order: R first, N, Z last
        f32x4 accRa = MFMA_F16(A0, Bf[0][0], bR4);
        f32x4 accRb = MFMA_F16(A1, Bf[0][1], zero4);
        f32x4 accNa = MFMA_F16(A0, Bf[2][0], bN4);
        f32x4 accNb = MFMA_F16(A1, Bf[2][1], zero4);
        f32x4 accZa = MFMA_F16(A0, Bf[1][0], bZ4);
        f32x4 accZb = MFMA_F16(A1, Bf[1][1], zero4);

        f32x4 aR = accRa + accRb;
        f32x4 aN = accNa + accNb;
        f32x4 aZ = accZa + accZb;

        f32x4 ar = xv * wr2 + aR;
        f32x4 Er = {__builtin_amdgcn_exp2f(ar[0]), __builtin_amdgcn_exp2f(ar[1]),
                    __builtin_amdgcn_exp2f(ar[2]), __builtin_amdgcn_exp2f(ar[3])};
        f32x4 DR = Er + 1.0f;
        f32x4 r  = {__builtin_amdgcn_rcpf(DR[0]), __builtin_amdgcn_rcpf(DR[1]),
                    __builtin_amdgcn_rcpf(DR[2]), __builtin_amdgcn_rcpf(DR[3])};
        f32x4 xn = xv * wn2 + bihn2;
        f32x4 an = r * aN + xn;
        f32x4 En = {__builtin_amdgcn_exp2f(an[0]), __builtin_amdgcn_exp2f(an[1]),
                    __builtin_amdgcn_exp2f(an[2]), __builtin_amdgcn_exp2f(an[3])};
        f32x4 DN = En + 1.0f;
        f32x4 az = xv * wz2 + aZ;
        f32x4 Ez = {__builtin_amdgcn_exp2f(az[0]), __builtin_amdgcn_exp2f(az[1]),
                    __builtin_amdgcn_exp2f(az[2]), __builtin_amdgcn_exp2f(az[3])};
        f32x4 DZ = Ez + 1.0f;
        f32x4 P  = DZ * DN;
        f32x4 iq = {__builtin_amdgcn_rcpf(P[0]), __builtin_amdgcn_rcpf(P[1]),
                    __builtin_amdgcn_rcpf(P[2]), __builtin_amdgcn_rcpf(P[3])};
        f32x4 z  = iq * DN;                  // = 1/DZ = sigmoid(pre_z)
        f32x4 rn = iq * DZ;                  // = 1/DN
        f32x4 n  = rn * -2.0f + 1.0f;        // tanh
        f32x4 s  = rn *  2.0f + hm1;         // h_prev - n
        f32x4 hn = z * s + n;                // (1-z)n + z h

        hlast = hn;
        hm1   = hn - 1.0f;

        h16x2 pk01 = __builtin_amdgcn_cvt_pkrtz(hn[0], hn[1]);
        h16x2 pk23 = __builtin_amdgcn_cvt_pkrtz(hn[2], hn[3]);
        unsigned u01 = __builtin_bit_cast(unsigned, pk01);
        unsigned u23 = __builtin_bit_cast(unsigned, pk23);
        short* wh = (short*)hbuf + (cur ^ 1) * 1024;
        wh[wa[0]] = (short)(u01 & 0xffffu);
        wh[wa[1]] = (short)(u01 >> 16);
        wh[wa[2]] = (short)(u23 & 0xffffu);
        wh[wa[3]] = (short)(u23 >> 16);
    };

    for (int t = 0; t < TT; t += 4) {
        f32x4 xa0 = *(const f32x4*)(xr0 + t);
        f32x4 xa1 = *(const f32x4*)(xr1 + t);
        f32x4 xa2 = *(const f32x4*)(xr2 + t);
        f32x4 xa3 = *(const f32x4*)(xr3 + t);
        step(0, f32x4{xa0[0], xa1[0], xa2[0], xa3[0]});
        step(1, f32x4{xa0[1], xa1[1], xa2[1], xa3[1]});
        step(0, f32x4{xa0[2], xa1[2], xa2[2], xa3[2]});
        step(1, f32x4{xa0[3], xa1[3], xa2[3], xa3[3]});
    }

    // ---- epilogue: out[b] = sum_q h[b][q]*Wout[q] + bout ----
    float p0 = hlast[0] * wo;
    float p1 = hlast[1] * wo;
    float p2 = hlast[2] * wo;
    float p3 = hlast[3] * wo;
    #pragma unroll
    for (int mask = 1; mask <= 8; mask <<= 1) {
        p0 += __shfl_xor(p0, mask, 64);
        p1 += __shfl_xor(p1, mask, 64);
        p2 += __shfl_xor(p2, mask, 64);
        p3 += __shfl_xor(p3, mask, 64);
    }
    if (n16 == 0) {
        outp[w][quad * 4 + 0] = p0;
        outp[w][quad * 4 + 1] = p1;
        outp[w][quad * 4 + 2] = p2;
        outp[w][quad * 4 + 3] = p3;
    }
    __syncthreads();
    if (tid < BTW) {
        out[b0 + tid] = outp[0][tid] + outp[1][tid] + outp[2][tid] + outp[3][tid] + bout[0];
    }
}

extern "C" void kernel_launch(void* const* d_in, const int* in_sizes, int n_in,
                              void* d_out, int out_size, void* d_ws, size_t ws_size,
                              hipStream_t stream) {
    (void)in_sizes; (void)n_in; (void)d_ws; (void)ws_size; (void)out_size;
    const float* x    = (const float*)d_in[0];
    const float* Wih  = (const float*)d_in[1];
    const float* Whh  = (const float*)d_in[2];
    const float* bih  = (const float*)d_in[3];
    const float* bhh  = (const float*)d_in[4];
    const float* Wout = (const float*)d_in[5];
    const float* bout = (const float*)d_in[6];
    float* out = (float*)d_out;

    gru_scan_kernel<<<dim3(4096 / BTW), dim3(256), 0, stream>>>(
        x, Wih, Whh, bih, bhh, Wout, bout, out);
}

// Round 6
// 249.577 us; speedup vs baseline: 1.1328x; 1.0246x over previous
//
#include <hip/hip_runtime.h>
#include <stdint.h>

#define TT 512
#define BTW 16   // 2 sets x 8 batches; 4096/16 = 256 wgs -> 1 wg/CU
#define XSTR 516 // x row stride (floats)

typedef float    f32x4 __attribute__((ext_vector_type(4)));
typedef float    f32x2 __attribute__((ext_vector_type(2)));
typedef short    s16x8 __attribute__((ext_vector_type(8)));
typedef __fp16   h16x2 __attribute__((ext_vector_type(2)));
typedef _Float16 f16x8 __attribute__((ext_vector_type(8)));

#define MFMA_F16(A, B, C) \
    __builtin_amdgcn_mfma_f32_16x16x32_f16( \
        __builtin_bit_cast(f16x8, (A)), (B), (C), 0, 0, 0)

#define LOG2E  1.442695040888963f
#define LOG2E2 2.885390081777927f

// R13 (resubmit; prior bench died to container infra, no signal):
// two-set interleave. Lessons: cross-wg TLP phase-locks (R10/R11);
// bare chain alone = 975 cyc/step (R12). Fix: interleave TWO independent
// 8-batch recurrences INSIDE each wave -- compile-time deterministic
// latency hiding, immune to phase-locking. Each set = R9's proven 153us
// machinery verbatim (swizzled zero-conflict exchange, f32x2 gate math,
// chained MFMAs, dbuf). 1 wg/CU (R12 proved zero contention), one
// barrier per round (= 1 step of BOTH sets -> half R9's barrier rate).
// Round: bar -> {read,6 MFMA}x2 -> math+write set0 (covers set1 MFMA
// latency) -> math+write set1 (covers set0 writes).
__global__ __launch_bounds__(256, 1) void gru_scan_kernel(
    const float* __restrict__ x,     // (4096, 512, 1)
    const float* __restrict__ Wih,   // (192, 1)
    const float* __restrict__ Whh,   // (192, 64)
    const float* __restrict__ bih,   // (192)
    const float* __restrict__ bhh,   // (192)
    const float* __restrict__ Wout,  // (1, 64)
    const float* __restrict__ bout,  // (1)
    float* __restrict__ out)         // (4096, 1)
{
    __shared__ __align__(16) float xs[BTW * XSTR];    // 33 KB
    __shared__ __align__(16) short hbuf[2][2][1024];  // [set][dbuf][slot*8+j], 8 KB
    __shared__ float outp[2][4][8];                   // [set][wave][batch-in-set]

    const int tid  = threadIdx.x;
    const int w    = tid >> 6;
    const int L    = tid & 63;
    const int n16  = L & 15;
    const int quad = L >> 4;
    const int q    = w * 16 + n16;   // hidden col owned by this lane
    const int bb0  = blockIdx.x * BTW;

    // ---- stage x batch-major: xs[b][t] (2048 f32x4, 8 per thread) ----
    #pragma unroll
    for (int k = 0; k < 8; ++k) {
        int idx = tid + k * 256;          // 0..2047
        int row = idx >> 7;               // batch row 0..15
        int t4  = idx & 127;              // t/4
        f32x4 v = *(const f32x4*)(x + (size_t)(bb0 + row) * TT + t4 * 4);
        *(f32x4*)(xs + row * XSTR + t4 * 4) = v;
    }
    // ---- zero all four h buffers (8192 B = 2048 u32, 8 per thread) ----
    {
        unsigned* hz = (unsigned*)hbuf;
        #pragma unroll
        for (int k = 0; k < 8; ++k) hz[tid + k * 256] = 0u;
    }

    // ---- per-lane constants (gate scales folded) ----
    const float wr2   = -LOG2E  * Wih[q];
    const float wz2   = -LOG2E  * Wih[64 + q];
    const float wn2   =  LOG2E2 * Wih[128 + q];
    const float bR2   = -LOG2E  * (bih[q]      + bhh[q]);
    const float bZ2   = -LOG2E  * (bih[64 + q] + bhh[64 + q]);
    const float bN2   =  LOG2E2 * bhh[128 + q];
    const float bihn2 =  LOG2E2 * bih[128 + q];
    const float wo    = Wout[q];

    const f32x4 bR4 = {bR2, bR2, bR2, bR2};
    const f32x4 bZ4 = {bZ2, bZ2, bZ2, bZ2};
    const f32x4 bN4 = {bN2, bN2, bN2, bN2};

    // ---- W_hh B-fragments (scaled), fp16 RNE ----
    f16x8 Bf[3][2];
    #pragma unroll
    for (int g = 0; g < 3; ++g) {
        const float sg = (g == 2) ? LOG2E2 : -LOG2E;
        #pragma unroll
        for (int c = 0; c < 2; ++c) {
            const float* p = Whh + ((g * 64 + q) * 64 + c * 32 + quad * 8);
            #pragma unroll
            for (int j = 0; j < 8; ++j)
                Bf[g][c][j] = (_Float16)(p[j] * sg);
        }
    }

    // ---- R9's proven zero-conflict exchange addressing (verbatim) ----
    const int kg   = q >> 3;
    const int sxor = (kg & 1) * 4;
    int waddr[2];
    #pragma unroll
    for (int p = 0; p < 2; ++p)
        waddr[p] = (kg * 16 + ((p * 4 + quad) ^ sxor)) * 8 + (q & 7);

    const int permx = ((n16 & 3) * 4 + (n16 >> 2)) ^ ((quad & 1) * 4);
    const int rslot = quad * 16 + permx;

    const s16x8* hb0 = (const s16x8*)hbuf[0];   // set 0: 2x128 slots
    const s16x8* hb1 = (const s16x8*)hbuf[1];   // set 1

    // x rows: set s covers batches s*8 + quad*2 + {0,1}
    const float* x00 = xs + (     quad * 2    ) * XSTR;
    const float* x01 = xs + (     quad * 2 + 1) * XSTR;
    const float* x10 = xs + (8 +  quad * 2    ) * XSTR;
    const float* x11 = xs + (8 +  quad * 2 + 1) * XSTR;

    // persistent h per set (fp32), lane's batches = quad*2 + {0,1}
    float hD0[2] = {0.f, 0.f};  f32x2 hm10 = {-1.f, -1.f};
    float hD1[2] = {0.f, 0.f};  f32x2 hm11 = {-1.f, -1.f};

    // gate math + h update + LDS write for one set (R9's f32x2 body,
    // hm1 variant proven in R12)
    auto gmath = [&](const f32x4& aR, const f32x4& aN, const f32x4& aZ,
                     f32x2 xv, f32x2& hm1v, float* hDv, short* wh) {
        f32x2 aRp = {aR[0], aR[1]};
        f32x2 aNp = {aN[0], aN[1]};
        f32x2 aZp = {aZ[0], aZ[1]};

        f32x2 ar = xv * wr2 + aRp;
        f32x2 Er = {__builtin_amdgcn_exp2f(ar[0]), __builtin_amdgcn_exp2f(ar[1])};
        f32x2 DR = Er + 1.0f;
        f32x2 r  = {__builtin_amdgcn_rcpf(DR[0]), __builtin_amdgcn_rcpf(DR[1])};
        f32x2 xn = xv * wn2 + bihn2;
        f32x2 an = r * aNp + xn;
        f32x2 En = {__builtin_amdgcn_exp2f(an[0]), __builtin_amdgcn_exp2f(an[1])};
        f32x2 DN = En + 1.0f;
        f32x2 az = xv * wz2 + aZp;
        f32x2 Ez = {__builtin_amdgcn_exp2f(az[0]), __builtin_amdgcn_exp2f(az[1])};
        f32x2 DZ = Ez + 1.0f;
        f32x2 P  = DZ * DN;
        f32x2 iq = {__builtin_amdgcn_rcpf(P[0]), __builtin_amdgcn_rcpf(P[1])};
        f32x2 z  = iq * DN;                  // = 1/DZ = sigmoid(pre_z)
        f32x2 rn = iq * DZ;                  // = 1/DN
        f32x2 n  = rn * -2.0f + 1.0f;        // tanh
        f32x2 s  = rn *  2.0f + hm1v;        // h_prev - n
        f32x2 hn = z * s + n;                // (1-z)n + z h

        hDv[0] = hn[0]; hDv[1] = hn[1];
        hm1v = hn - 1.0f;

        h16x2 hpk = __builtin_amdgcn_cvt_pkrtz(hn[0], hn[1]);
        unsigned upk = __builtin_bit_cast(unsigned, hpk);
        wh[waddr[0]] = (short)(upk & 0xffffu);
        wh[waddr[1]] = (short)(upk >> 16);
    };

    auto round = [&](int cur, f32x2 xv0, f32x2 xv1) {
        __syncthreads();

        // both sets' A-fragments (4x ds_read_b128, independent)
        s16x8 A00 = hb0[cur * 128 +      rslot];
        s16x8 A01 = hb0[cur * 128 + 64 + rslot];
        s16x8 A10 = hb1[cur * 128 +      rslot];
        s16x8 A11 = hb1[cur * 128 + 64 + rslot];

        // set 0 MFMAs (chained C like R9; order R,N,Z = consumption order)
        f32x4 aR0 = MFMA_F16(A00, Bf[0][0], bR4); aR0 = MFMA_F16(A01, Bf[0][1], aR0);
        f32x4 aN0 = MFMA_F16(A00, Bf[2][0], bN4); aN0 = MFMA_F16(A01, Bf[2][1], aN0);
        f32x4 aZ0 = MFMA_F16(A00, Bf[1][0], bZ4); aZ0 = MFMA_F16(A01, Bf[1][1], aZ0);
        // set 1 MFMAs (issue under set 0's math window)
        f32x4 aR1 = MFMA_F16(A10, Bf[0][0], bR4); aR1 = MFMA_F16(A11, Bf[0][1], aR1);
        f32x4 aN1 = MFMA_F16(A10, Bf[2][0], bN4); aN1 = MFMA_F16(A11, Bf[2][1], aN1);
        f32x4 aZ1 = MFMA_F16(A10, Bf[1][0], bZ4); aZ1 = MFMA_F16(A11, Bf[1][1], aZ1);

        gmath(aR0, aN0, aZ0, xv0, hm10, hD0, (short*)hbuf[0] + (cur ^ 1) * 1024);
        gmath(aR1, aN1, aZ1, xv1, hm11, hD1, (short*)hbuf[1] + (cur ^ 1) * 1024);
    };

    for (int t = 0; t < TT; t += 4) {
        f32x4 xa0 = *(const f32x4*)(x00 + t);
        f32x4 xb0 = *(const f32x4*)(x01 + t);
        f32x4 xa1 = *(const f32x4*)(x10 + t);
        f32x4 xb1 = *(const f32x4*)(x11 + t);
        round(0, f32x2{xa0[0], xb0[0]}, f32x2{xa1[0], xb1[0]});
        round(1, f32x2{xa0[1], xb0[1]}, f32x2{xa1[1], xb1[1]});
        round(0, f32x2{xa0[2], xb0[2]}, f32x2{xa1[2], xb1[2]});
        round(1, f32x2{xa0[3], xb0[3]}, f32x2{xa1[3], xb1[3]});
    }

    // ---- epilogue: out[b] = sum_q h[b][q]*Wout[q] + bout ----
    float p00 = hD0[0] * wo;
    float p01 = hD0[1] * wo;
    float p10 = hD1[0] * wo;
    float p11 = hD1[1] * wo;
    #pragma unroll
    for (int mask = 1; mask <= 8; mask <<= 1) {
        p00 += __shfl_xor(p00, mask, 64);
        p01 += __shfl_xor(p01, mask, 64);
        p10 += __shfl_xor(p10, mask, 64);
        p11 += __shfl_xor(p11, mask, 64);
    }
    if (n16 == 0) {
        outp[0][w][quad * 2]     = p00;
        outp[0][w][quad * 2 + 1] = p01;
        outp[1][w][quad * 2]     = p10;
        outp[1][w][quad * 2 + 1] = p11;
    }
    __syncthreads();
    if (tid < BTW) {
        int ss = tid >> 3;        // set
        int c  = tid & 7;         // batch within set
        out[bb0 + tid] = outp[ss][0][c] + outp[ss][1][c] +
                         outp[ss][2][c] + outp[ss][3][c] + bout[0];
    }
}

extern "C" void kernel_launch(void* const* d_in, const int* in_sizes, int n_in,
                              void* d_out, int out_size, void* d_ws, size_t ws_size,
                              hipStream_t stream) {
    (void)in_sizes; (void)n_in; (void)d_ws; (void)ws_size; (void)out_size;
    const float* x    = (const float*)d_in[0];
    const float* Wih  = (const float*)d_in[1];
    const float* Whh  = (const float*)d_in[2];
    const float* bih  = (const float*)d_in[3];
    const float* bhh  = (const float*)d_in[4];
    const float* Wout = (const float*)d_in[5];
    const float* bout = (const float*)d_in[6];
    float* out = (float*)d_out;

    gru_scan_kernel<<<dim3(4096 / BTW), dim3(256), 0, stream>>>(
        x, Wih, Whh, bih, bhh, Wout, bout, out);
}